// Round 3
// baseline (1791.642 us; speedup 1.0000x reference)
//
#include <hip/hip_runtime.h>
#include <hip/hip_bf16.h>
#include <math.h>

#define BN_ 8192
#define TT 18
#define NBITS 6
#define HH 256
#define G3 768

typedef __hip_bfloat16 hbf16;
typedef __bf16 bf16x8 __attribute__((ext_vector_type(8)));
typedef float f32x4 __attribute__((ext_vector_type(4)));

__device__ inline float sigm(float x){ return 1.0f/(1.0f + expf(-x)); }
__device__ inline float ldx(const void* p, int i, int bf){
    if(bf){ unsigned short u = ((const unsigned short*)p)[i]; return __uint_as_float(((unsigned)u)<<16); }
    return ((const float*)p)[i];
}
__device__ inline __bf16 f2b(float f){ hbf16 h = __float2bfloat16(f); return *reinterpret_cast<__bf16*>(&h); }
__device__ inline float b2f(__bf16 b){ unsigned short u = *reinterpret_cast<unsigned short*>(&b); return __uint_as_float(((unsigned)u)<<16); }
__device__ inline unsigned pack2(float a, float b){
    hbf16 lo = __float2bfloat16(a), hi = __float2bfloat16(b);
    return (unsigned)*(unsigned short*)&lo | ((unsigned)*(unsigned short*)&hi << 16);
}

// global->LDS direct DMA, 16B per lane. LDS dest must be wave-uniform base (+lane*16 by HW).
__device__ __forceinline__ void gld_lds16(const void* g, void* l){
    __builtin_amdgcn_global_load_lds(
        (const __attribute__((address_space(1))) unsigned int*)g,
        (__attribute__((address_space(3))) unsigned int*)l, 16, 0, 0);
}

// -------- fills --------
__global__ __launch_bounds__(256) void fillz(float* __restrict__ p, int n){
    for(int i = blockIdx.x*256 + threadIdx.x; i < n; i += gridDim.x*256) p[i] = 0.0f;
}
__global__ __launch_bounds__(256) void fillb(__bf16* __restrict__ p, int n){
    for(int i = blockIdx.x*256 + threadIdx.x; i < n; i += gridDim.x*256) p[i] = f2b(0.0f);
}

// -------- dtype detect + normalized per-step weights --------
__global__ void prep_w(const void* wp, const void* wm, unsigned* flag,
                       float* wpn, float* wfn, float* wbn){
    if(threadIdx.x==0 && blockIdx.x==0){
        unsigned w0 = *(const unsigned*)wp;               // weight_power is all-ones
        int bf = ((w0 >> 16) == (w0 & 0xFFFFu)) ? 1 : 0;
        flag[0] = (unsigned)bf;
        float s=0; for(int t=0;t<TT;t++){ float v=ldx(wp,t,bf); s += v*v; }
        for(int t=0;t<TT;t++){ float v=ldx(wp,t,bf); wpn[t] = sqrtf(v*v*TT/s); }
        float sf=0, sb=0;
        for(int t=0;t<TT;t++){ float f=ldx(wm,2*t,bf), b=ldx(wm,2*t+1,bf); sf += f*f; sb += b*b; }
        for(int t=0;t<TT;t++){
            float f=ldx(wm,2*t,bf), b=ldx(wm,2*t+1,bf);
            wfn[t] = sqrtf(f*f*TT/sf);
            wbn[t] = sqrtf(b*b*TT/sb);
        }
    }
}

// -------- conversions: mode1 = weight row-perm -> bf16; mode0 = bias f32; mode2 = [B,T]->[T,B] f32 --------
struct CJ { const void* src; void* dst; int n; int K; int mode; };
struct CJs { CJ j[20]; };
__global__ __launch_bounds__(256) void conv_all(CJs J, const unsigned* __restrict__ flagp){
    const int bf = (int)*flagp;
    CJ c = J.j[blockIdx.y];
    for(int i = blockIdx.x*256 + threadIdx.x; i < c.n; i += gridDim.x*256){
        if(c.mode==1){
            int row = i / c.K, k = i - row*c.K;
            int g = row>>8, jj = row&255;
            int prow = ((jj>>4)*48) + g*16 + (jj&15);
            ((__bf16*)c.dst)[(size_t)prow*c.K + k] = f2b(ldx(c.src, i, bf));
        }else if(c.mode==2){
            int t = i >> 13, b = i & (BN_-1);
            ((float*)c.dst)[i] = ldx(c.src, b*TT + t, bf);
        }else{
            ((float*)c.dst)[i] = ldx(c.src, i, bf);
        }
    }
}

// -------- fused recurrent step: dual GEMM (gi, gh) + GRU cell + LDS-coalesced epilogue --------
// r12: global_load_lds staging (linear LDS dest + inverse-swizzled global src + swizzled read).
// r13: stats_emit folded into MODE0 prologue; head projection folded into MODE3 (neutral but
//      keeps dispatch count down).
// r14: K-loop software-pipelined (T3-minimum 2-phase): BK=32 double-buffered LDS
//      (2x14336 = 28672 B, same footprint -> 3 blocks/CU kept), STAGE(s+1) issued BEFORE
//      compute(s) so the __syncthreads vmcnt(0) drain lands after loads had the whole
//      compute phase (~340cy) to fly. Swizzle: slot ^ ((row>>1)&3), both-sides (rule 21).
//      MFMA accumulation order bit-identical to r13.
// MODE 0: enc layer0 (gh GEMM; gi = rank-7 from bits/z) + prev-step BN stats -> h, yseq[t-1]
// MODE 1: enc layer1 (gi,gh GEMMs) -> h + rowdot atomics into xt
// MODE 2: dec layer0 (gh GEMM; gi = y*wih+bih)                 -> h + s1 slice
// MODE 3: dec layer1 (gi K=512, gh K=256)                      -> h + head partials
struct FQ {
    const __bf16* A1; const __bf16* W1; int K1;   // K1 doubles as stats_on for MODE0
    const __bf16* A2; const __bf16* W2; int K2;
    const float* bgi; const float* bgh;
    const __bf16* h; __bf16* hout;
    const void* bits; const void* wih0raw; const void* bih0raw;                    // mode0 (bits=dlinW in mode3)
    const void* linw; float* xt;       // mode1: enc_lin row-dot dest | mode0: linw=elinb, xt=xtR | mode3: xt=pout_part
    const float* y; const void* wihraw; const void* bihraw; __bf16* s1t;           // mode2 | mode0: y=n1p, wihraw=n2p, s1t=yseq dest
    float* racc; const float* wct;     // mode0: racc=xtZ, wct=&wpn[t-1] | mode3: wct=&w_merge[t]
};
struct FQ2 { FQ q[2]; };

template<int MODE>
__global__ __launch_bounds__(256,3) void fused_step(FQ2 PP, const unsigned* __restrict__ flagp){
    const FQ P = PP.q[blockIdx.z];
    const int bf = (int)*flagp;
    __shared__ __align__(16) char smem[28672];   // 2 x (A 8192 + W 6144) double buffer
    __shared__ float zs[192];                   // mode0: z feedback per row (128) | mode3: W-head slice (192)
    __shared__ float sred[4], ssred[4];
    float*  T  = (float*)smem;                  // 128*33*4 = 16896 (reused after K-loop)
    const int tid = threadIdx.x;
    // XCD-aware swizzle: XCD = blockIdx.x -> contiguous m-band per XCD.
    const int mt = blockIdx.x*8 + (blockIdx.y>>3);
    const int jt = blockIdx.y & 7;
    const int m0 = mt*128;
    const int n0 = jt*96;
    const int lane = tid&63, wv = tid>>6;
    const int wvbase = tid & ~63;               // wv*64, wave-uniform
    const int wrow = wv>>1, wcol = wv&1;        // wave: 64 rows x 48 cols
    const int q = lane>>4, n15 = lane&15;

    // ---- pipelined K-loop geometry (compile-time) ----
    constexpr int S1  = (MODE==1) ? 8 : (MODE==3 ? 16 : 0);   // BK32 steps in phase0 (gi GEMM)
    constexpr int NST = S1 + 8;                               // + phase1 (gh GEMM, K=256)
    constexpr int KD1 = (MODE==3) ? 512 : 256;
    constexpr int KD2 = 256;
    const __bf16* pA1 = (S1>0) ? P.A1 + (size_t)m0*KD1 : (const __bf16*)nullptr;
    const __bf16* pW1 = (S1>0) ? P.W1 + (size_t)n0*KD1 : (const __bf16*)nullptr;
    const __bf16* pA2 = P.A2 + (size_t)m0*KD2;
    const __bf16* pW2 = P.W2 + (size_t)n0*KD2;
    const int r0 = tid>>2, sl0 = tid&3;              // chunk c = tid
    const int q0 = sl0 ^ ((r0>>1)&3);
    const int r1 = (256+tid)>>2, sl1 = tid&3;        // chunk c = 256+tid
    const int q1 = sl1 ^ ((r1>>1)&3);

    auto STG = [&](int s){
        const __bf16* A; const __bf16* W; int K; int k0;
        if(s < S1){ A = pA1; W = pW1; K = KD1; k0 = s*32; }
        else      { A = pA2; W = pW2; K = KD2; k0 = (s-S1)*32; }
        char* buf = smem + (s&1)*14336;
        // A-tile: 128x32 bf16 = 8192 B = 512 chunks (2/thread)
        gld_lds16(A + (size_t)r0*K + k0 + q0*8, buf + (size_t)wvbase*16);
        gld_lds16(A + (size_t)r1*K + k0 + q1*8, buf + (size_t)(256+wvbase)*16);
        // W-tile: 96x32 bf16 = 6144 B = 384 chunks (1.5/thread; waves 0,1 take the extra)
        gld_lds16(W + (size_t)r0*K + k0 + q0*8, buf + 8192 + (size_t)wvbase*16);
        if(tid < 128)
            gld_lds16(W + (size_t)r1*K + k0 + q1*8, buf + 8192 + (size_t)(256+wvbase)*16);
    };

    STG(0);   // prologue prefetch; drained by the next __syncthreads

    // ---- MODE0 prologue: redundant per-block BN stats of previous step (replaces stats_emit) ----
    if(MODE==0){
        if(P.K1){
            const float lbv = ldx(P.linw, 0, bf);
            const float wt  = P.wct[0];
            const float* __restrict__ xr = P.xt;
            float s=0.0f, ss=0.0f;
            const float4* x4 = (const float4*)xr;
            for(int i=tid;i<BN_/4;i+=256){
                float4 vv = x4[i];
                float a0=tanhf(vv.x+lbv), a1=tanhf(vv.y+lbv), a2=tanhf(vv.z+lbv), a3=tanhf(vv.w+lbv);
                s += a0+a1+a2+a3; ss += a0*a0+a1*a1+a2*a2+a3*a3;
            }
            #pragma unroll
            for(int o=32;o;o>>=1){ s += __shfl_xor(s,o); ss += __shfl_xor(ss,o); }
            if(lane==0){ sred[wv]=s; ssred[wv]=ss; }
            __syncthreads();
            float a = sred[0]+sred[1]+sred[2]+sred[3];
            float bq = ssred[0]+ssred[1]+ssred[2]+ssred[3];
            float mean = a/(float)BN_;
            float var = (bq - (float)BN_*mean*mean)/(float)(BN_-1);
            float rs = 1.0f/sqrtf(var);
            if(tid<128){
                int row = m0 + tid;
                float v = tanhf(xr[row]+lbv);
                float yv = (v-mean)*rs*wt + P.y[row];
                zs[tid] = yv + ((const float*)P.wihraw)[row];
                if(jt==0){ ((float*)P.s1t)[row] = yv; P.racc[row] = 0.0f; }
            }
        }else{
            if(tid<128) zs[tid] = 0.0f;
        }
        __syncthreads();
    }else{
        __syncthreads();
    }

    f32x4 accR[4], accZ[4], accN1[4], accN2[4];
    #pragma unroll
    for(int i=0;i<4;i++){ accR[i]=(f32x4){0,0,0,0}; accZ[i]=(f32x4){0,0,0,0};
                          accN1[i]=(f32x4){0,0,0,0}; accN2[i]=(f32x4){0,0,0,0}; }

    // ---- main pipelined loop: STAGE(s+1) || compute(s) ----
    #pragma unroll
    for(int s=0; s<NST; ++s){
        if(s+1 < NST) STG(s+1);
        const char* buf = smem + (s&1)*14336;
        const __bf16* Asb = (const __bf16*)buf;
        const __bf16* Wsb = (const __bf16*)(buf + 8192);
        bf16x8 af[4], bfr[3];
        #pragma unroll
        for(int i=0;i<4;i++){
            int R = wrow*64+i*16+n15;
            int col = q ^ ((R>>1)&3);
            af[i] = *(const bf16x8*)&Asb[R*32 + col*8];
        }
        #pragma unroll
        for(int g=0;g<3;g++){
            int RW = wcol*48+g*16+n15;
            int col = q ^ ((RW>>1)&3);
            bfr[g] = *(const bf16x8*)&Wsb[RW*32 + col*8];
        }
        #pragma unroll
        for(int i=0;i<4;i++){
            accR[i] = __builtin_amdgcn_mfma_f32_16x16x32_bf16(af[i], bfr[0], accR[i], 0,0,0);
            accZ[i] = __builtin_amdgcn_mfma_f32_16x16x32_bf16(af[i], bfr[1], accZ[i], 0,0,0);
            if(s < S1) accN1[i] = __builtin_amdgcn_mfma_f32_16x16x32_bf16(af[i], bfr[2], accN1[i], 0,0,0);
            else       accN2[i] = __builtin_amdgcn_mfma_f32_16x16x32_bf16(af[i], bfr[2], accN2[i], 0,0,0);
        }
        __syncthreads();
    }

    // ---- epilogue compute: lane owns hidden unit j for 16 rows; hn -> T (f32) ----
    const int jl = wcol*16 + n15;
    const int j  = jt*32 + jl;
    const float bghr = P.bgh[j], bghz = P.bgh[256+j], bghn = P.bgh[512+j];
    float bgir=0, bgiz=0, bgin=0;
    if(MODE==1 || MODE==3){ bgir = P.bgi[j]; bgiz = P.bgi[256+j]; bgin = P.bgi[512+j]; }
    float w0r[7], w0z[7], w0n[7];
    if(MODE==0){
        #pragma unroll
        for(int k=0;k<7;k++){
            w0r[k] = ldx(P.wih0raw, (j    )*7+k, bf);
            w0z[k] = ldx(P.wih0raw, (j+256)*7+k, bf);
            w0n[k] = ldx(P.wih0raw, (j+512)*7+k, bf);
        }
        bgir = ldx(P.bih0raw, j, bf); bgiz = ldx(P.bih0raw, j+256, bf); bgin = ldx(P.bih0raw, j+512, bf);
    }
    float wy_r=0, wy_z=0, wy_n=0;
    if(MODE==2){
        wy_r = ldx(P.wihraw, j, bf); wy_z = ldx(P.wihraw, j+256, bf); wy_n = ldx(P.wihraw, j+512, bf);
        bgir = ldx(P.bihraw, j, bf); bgiz = ldx(P.bihraw, j+256, bf); bgin = ldx(P.bihraw, j+512, bf);
    }
    const float linwj = (MODE==1) ? ldx(P.linw, j, bf) : 0.0f;

    #pragma unroll
    for(int i=0;i<4;i++){
        const int rbl = wrow*64 + i*16 + q*4;
        float vred[4];
        #pragma unroll
        for(int r=0;r<4;r++){
            const int row_l = rbl + r;
            const int row = m0 + row_l;
            float gir, giz, gin;
            if(MODE==1 || MODE==3){
                gir = bgir; giz = bgiz; gin = accN1[i][r] + bgin;
            }else if(MODE==0){
                gir = bgir; giz = bgiz; gin = bgin;
                #pragma unroll
                for(int k=0;k<NBITS;k++){
                    float bv = ldx(P.bits, row*NBITS+k, bf);
                    gir += bv*w0r[k]; giz += bv*w0z[k]; gin += bv*w0n[k];
                }
                float zb = zs[row_l];
                gir += zb*w0r[6]; giz += zb*w0z[6]; gin += zb*w0n[6];
            }else{ // MODE==2
                float yv = P.y[row];
                gir = yv*wy_r + bgir; giz = yv*wy_z + bgiz; gin = yv*wy_n + bgin;
            }
            float rr = sigm(gir + accR[i][r] + bghr);
            float zz = sigm(giz + accZ[i][r] + bghz);
            float nn = tanhf(gin + rr*(accN2[i][r] + bghn));
            float hold = b2f(P.h[(size_t)row*HH + j]);
            float hn = (1.0f - zz)*nn + zz*hold;
            T[row_l*33 + jl] = hn;
            if(MODE==1) vred[r] = hn*linwj;
        }
        if(MODE==1){
            #pragma unroll
            for(int r=0;r<4;r++){
                float v = vred[r];
                #pragma unroll
                for(int m=1;m<16;m<<=1) v += __shfl_xor(v, m);
                if(n15==0) atomicAdd(&P.xt[m0+rbl+r], v);
            }
        }
    }
    if(MODE==3 && tid<192){   // stage dlinW slice: k=tid>>5 (6 rows), 32 cols of this block
        int k = tid>>5, jj = tid&31;
        zs[tid] = ldx(P.bits, k*512 + (int)blockIdx.z*256 + jt*32 + jj, bf);
    }
    __syncthreads();

    // ---- coalesced write-out: 4 lanes per row x 8 j each ----
    const int rw2 = tid>>2, cw = tid&3;
    #pragma unroll
    for(int pass=0; pass<2; pass++){
        const int row_l = pass*64 + rw2;
        const int row = m0 + row_l;
        float v[8];
        #pragma unroll
        for(int u=0;u<8;u++) v[u] = T[row_l*33 + cw*8 + u];
        uint4 pkv = { pack2(v[0],v[1]), pack2(v[2],v[3]), pack2(v[4],v[5]), pack2(v[6],v[7]) };
        *(uint4*)&P.hout[(size_t)row*HH + jt*32 + cw*8] = pkv;
        if(MODE==2) *(uint4*)&P.s1t[(size_t)row*512 + jt*32 + cw*8] = pkv;
    }
    if(MODE==3){
        // head partial: pp[(row,k)] += wct * (T-row . W-slice). Private (jt,z) slice -> no atomics.
        float* pp = P.xt + (size_t)(jt + 8*(int)blockIdx.z)*(BN_*NBITS);
        const float wct3 = P.wct[0];
        #pragma unroll
        for(int u=0;u<3;u++){
            int idx = tid + 256*u;
            int row_l = idx/6, k = idx - row_l*6;
            float dot = 0.0f;
            #pragma unroll
            for(int jj=0;jj<32;jj++) dot += T[row_l*33+jj]*zs[k*32+jj];
            size_t gi = (size_t)(m0+row_l)*NBITS + k;
            pp[gi] += wct3*dot;
        }
    }
}

// -------- fused tanh + batch-norm stats (ddof=1) + y emit; only used for the final step t=17 --------
__global__ __launch_bounds__(1024) void stats_emit(float* __restrict__ xt, const void* __restrict__ lb,
        const float* __restrict__ wpn, int t, const float* __restrict__ n1t, const float* __restrict__ n2t,
        float* __restrict__ yseq, float* __restrict__ zf, const unsigned* __restrict__ flagp){
    const int bf = (int)*flagp;
    const float lbv = ldx(lb, 0, bf);
    int tid = threadIdx.x;
    float s=0.0f, ss=0.0f;
    for(int i=tid;i<BN_;i+=1024){ float v = tanhf(xt[i] + lbv); s += v; ss += v*v; }
    #pragma unroll
    for(int o=32;o;o>>=1){ s += __shfl_down(s,o); ss += __shfl_down(ss,o); }
    __shared__ float S[16], SS[16], stm[2];
    if((tid&63)==0){ S[tid>>6]=s; SS[tid>>6]=ss; }
    __syncthreads();
    if(tid==0){
        float a=0.0f, b=0.0f;
        for(int i=0;i<16;i++){ a+=S[i]; b+=SS[i]; }
        float mean = a/(float)BN_;
        float var = (b - (float)BN_*mean*mean)/(float)(BN_-1);
        stm[0]=mean; stm[1]=1.0f/sqrtf(var);
    }
    __syncthreads();
    const float mean=stm[0], rs=stm[1], wt=wpn[t];
    for(int i=tid;i<BN_;i+=1024){
        float v = tanhf(xt[i] + lbv);
        float y = (v-mean)*rs*wt + n1t[i];
        yseq[(size_t)t*BN_ + i] = y;
        zf[i] = y + n2t[i];
        xt[i] = 0.0f;
    }
}

// -------- head: sum 16 partial slices + bias + sigmoid --------
__global__ __launch_bounds__(256) void out_head(const float* __restrict__ pp, const void* __restrict__ bias,
        void* __restrict__ out, const unsigned* __restrict__ flagp){
    const int bf = (int)*flagp;
    int i = blockIdx.x*256 + threadIdx.x;
    if(i >= BN_*NBITS) return;
    float s = 0.0f;
    #pragma unroll
    for(int k=0;k<16;k++) s += pp[(size_t)k*(BN_*NBITS) + i];
    int kk = i - (i/6)*6;
    float v = sigm(s + ldx(bias, kk, bf));
    if(bf) ((hbf16*)out)[i] = __float2bfloat16(v);
    else   ((float*)out)[i] = v;
}

extern "C" void kernel_launch(void* const* d_in, const int* in_sizes, int n_in,
                              void* d_out, int out_size, void* d_ws, size_t ws_size,
                              hipStream_t stream)
{
    (void)in_sizes; (void)n_in; (void)out_size;
    const void* bits  = d_in[0];
    const void* n1    = d_in[1];
    const void* n2    = d_in[2];
    const void* eWih0 = d_in[3];
    const void* eWhh0 = d_in[4];
    const void* ebih0 = d_in[5];
    const void* ebhh0 = d_in[6];
    const void* eWih1 = d_in[7];
    const void* eWhh1 = d_in[8];
    const void* ebih1 = d_in[9];
    const void* ebhh1 = d_in[10];
    const void* elinW = d_in[11];
    const void* elinb = d_in[12];
    const void* wpow  = d_in[13];
    const void* dWih0f= d_in[14];
    const void* dWhh0f= d_in[15];
    const void* dbih0f= d_in[16];
    const void* dbhh0f= d_in[17];
    const void* dWih0b= d_in[18];
    const void* dWhh0b= d_in[19];
    const void* dbih0b= d_in[20];
    const void* dbhh0b= d_in[21];
    const void* dWih1f= d_in[22];
    const void* dWhh1f= d_in[23];
    const void* dbih1f= d_in[24];
    const void* dbhh1f= d_in[25];
    const void* dWih1b= d_in[26];
    const void* dWhh1b= d_in[27];
    const void* dbih1b= d_in[28];
    const void* dbhh1b= d_in[29];
    const void* dlinW = d_in[30];
    const void* dlinb = d_in[31];
    const void* wmrg  = d_in[32];

    float* base = (float*)d_ws;
    size_t off = 0;
    auto alloc  = [&](size_t n){ float* p = base + off; off += (n + 63) & ~(size_t)63; return p; };
    auto allocb = [&](size_t n){ __bf16* p = (__bf16*)(base + off); off += ((n/2) + 63) & ~(size_t)63; return p; };
    unsigned* flag = (unsigned*)alloc(64);
    float* wpn = alloc(TT); float* wfn = alloc(TT); float* wbn = alloc(TT);
    const int WK = HH*G3;   // 196608
    __bf16* WeHH0 = allocb(WK);  __bf16* WeIH1 = allocb(WK);  __bf16* WeHH1 = allocb(WK);
    __bf16* Wd0f  = allocb(WK);  __bf16* Wd0b  = allocb(WK);
    __bf16* Wd1fI = allocb(2*WK);__bf16* Wd1bI = allocb(2*WK);
    __bf16* Wd1fH = allocb(WK);  __bf16* Wd1bH = allocb(WK);
    float* BeHH0 = alloc(G3); float* BeIH1 = alloc(G3); float* BeHH1 = alloc(G3);
    float* Bd0f  = alloc(G3); float* Bd0b  = alloc(G3);
    float* Bd1fI = alloc(G3); float* Bd1bI = alloc(G3);
    float* Bd1fH = alloc(G3); float* Bd1bH = alloc(G3);
    const size_t NH = (size_t)BN_*HH;
    __bf16* X0 = allocb(NH);  __bf16* X1 = allocb(NH);
    __bf16* Y0 = allocb(NH);  __bf16* Y1 = allocb(NH);
    float* pout = alloc((size_t)16*BN_*NBITS);            // 16 head-partial slices
    float* xtA = alloc(BN_);
    float* xtB = alloc(BN_);
    float* zf  = alloc(BN_);
    float* yseq= alloc((size_t)TT*BN_);
    float* n1t = alloc((size_t)TT*BN_);
    float* n2t = alloc((size_t)TT*BN_);
    __bf16* s1 = allocb((size_t)TT*BN_*512);
    size_t need = off*sizeof(float);
    if(ws_size < need) return;

    // ---- prep ----
    prep_w<<<1,64,0,stream>>>(wpow, wmrg, flag, wpn, wfn, wbn);
    CJs J;
    const void* ws_src[20] = {eWhh0,eWih1,eWhh1,dWhh0f,dWhh0b,dWih1f,dWih1b,dWhh1f,dWhh1b,
                              ebhh0,ebih1,ebhh1,dbhh0f,dbhh0b,dbih1f,dbih1b,dbhh1f,dbhh1b, n1, n2};
    void* ws_dst[20] = {WeHH0,WeIH1,WeHH1,Wd0f,Wd0b,Wd1fI,Wd1bI,Wd1fH,Wd1bH,
                        BeHH0,BeIH1,BeHH1,Bd0f,Bd0b,Bd1fI,Bd1bI,Bd1fH,Bd1bH, n1t, n2t};
    int ws_n[20] = {WK,WK,WK,WK,WK,2*WK,2*WK,WK,WK, G3,G3,G3,G3,G3,G3,G3,G3,G3, TT*BN_, TT*BN_};
    int ws_K[20] = {256,256,256,256,256,512,512,256,256, 0,0,0,0,0,0,0,0,0, 0,0};
    int ws_m[20] = {1,1,1,1,1,1,1,1,1, 0,0,0,0,0,0,0,0,0, 2,2};
    for(int i=0;i<20;i++){ J.j[i] = {ws_src[i], ws_dst[i], ws_n[i], ws_K[i], ws_m[i]}; }
    conv_all<<<dim3(768,20),256,0,stream>>>(J, flag);
    fillb<<<1024,256,0,stream>>>(X0, (int)NH);
    fillb<<<1024,256,0,stream>>>(Y0, (int)NH);
    fillz<<<32,256,0,stream>>>(xtA, BN_);
    fillz<<<32,256,0,stream>>>(xtB, BN_);
    fillz<<<192,256,0,stream>>>(pout, 16*BN_*NBITS);

    dim3 g1(8, 64, 1), g2(8, 64, 2);
    __bf16* X[2] = {X0, X1};
    __bf16* Y[2] = {Y0, Y1};
    float* xts[2] = {xtA, xtB};

    // ---- encoder: 18 steps, 2 dispatches each (stats fused into next MODE0) ----
    int p = 0;
    for(int t=0;t<TT;t++){
        FQ2 P0{}; FQ2 P1{};
        FQ& a = P0.q[0];
        a.A2=X[p]; a.W2=WeHH0; a.K2=HH; a.bgh=BeHH0; a.h=X[p]; a.hout=X[1-p];
        a.bits=bits; a.wih0raw=eWih0; a.bih0raw=ebih0;
        a.K1 = (t>0) ? 1 : 0;
        if(t>0){
            a.xt   = xts[(t-1)&1];                       // stats source (prev MODE1 atomics)
            a.racc = xts[t&1];                           // zero target (consumed by prev MODE0)
            a.y    = n1t + (size_t)(t-1)*BN_;
            a.wihraw = (const void*)(n2t + (size_t)(t-1)*BN_);
            a.s1t  = (__bf16*)(yseq + (size_t)(t-1)*BN_);
            a.wct  = wpn + (t-1);
            a.linw = elinb;
        }
        fused_step<0><<<g1,256,0,stream>>>(P0, flag);
        FQ& b = P1.q[0];
        b.A1=X[1-p]; b.W1=WeIH1; b.K1=HH; b.A2=Y[p]; b.W2=WeHH1; b.K2=HH;
        b.bgi=BeIH1; b.bgh=BeHH1; b.h=Y[p]; b.hout=Y[1-p];
        b.linw=elinW; b.xt=xts[t&1];
        fused_step<1><<<g1,256,0,stream>>>(P1, flag);
        p ^= 1;
    }
    stats_emit<<<1,1024,0,stream>>>(xts[(TT-1)&1], elinb, wpn, TT-1,
                                    n1t+(size_t)(TT-1)*BN_, n2t+(size_t)(TT-1)*BN_, yseq, zf, flag);

    // ---- decoder layer0: fwd (X) + bwd (Y) in one z=2 dispatch per step ----
    fillb<<<1024,256,0,stream>>>(X0, (int)NH);
    fillb<<<1024,256,0,stream>>>(Y0, (int)NH);
    p = 0;
    for(int i=0;i<TT;i++){
        int tf = i, tb = TT-1-i;
        FQ2 P{};
        FQ& a = P.q[0];
        a.A2=X[p]; a.W2=Wd0f; a.K2=HH; a.bgh=Bd0f; a.h=X[p]; a.hout=X[1-p];
        a.y=yseq+(size_t)tf*BN_; a.wihraw=dWih0f; a.bihraw=dbih0f; a.s1t=s1+(size_t)tf*BN_*512;
        FQ& b = P.q[1];
        b.A2=Y[p]; b.W2=Wd0b; b.K2=HH; b.bgh=Bd0b; b.h=Y[p]; b.hout=Y[1-p];
        b.y=yseq+(size_t)tb*BN_; b.wihraw=dWih0b; b.bihraw=dbih0b; b.s1t=s1+(size_t)tb*BN_*512+256;
        fused_step<2><<<g2,256,0,stream>>>(P, flag);
        p ^= 1;
    }

    // ---- decoder layer1: fwd (X) + bwd (Y) in one z=2 dispatch per step, head partials fused ----
    fillb<<<1024,256,0,stream>>>(X0, (int)NH);
    fillb<<<1024,256,0,stream>>>(Y0, (int)NH);
    p = 0;
    for(int i=0;i<TT;i++){
        int tf = i, tb = TT-1-i;
        FQ2 P{};
        FQ& a = P.q[0];
        a.A1=s1+(size_t)tf*BN_*512; a.W1=Wd1fI; a.K1=512;
        a.A2=X[p]; a.W2=Wd1fH; a.K2=HH; a.bgi=Bd1fI; a.bgh=Bd1fH; a.h=X[p]; a.hout=X[1-p];
        a.bits=dlinW; a.xt=pout; a.wct=wfn+tf;
        FQ& b = P.q[1];
        b.A1=s1+(size_t)tb*BN_*512; b.W1=Wd1bI; b.K1=512;
        b.A2=Y[p]; b.W2=Wd1bH; b.K2=HH; b.bgi=Bd1bI; b.bgh=Bd1bH; b.h=Y[p]; b.hout=Y[1-p];
        b.bits=dlinW; b.xt=pout; b.wct=wbn+tb;
        fused_step<3><<<g2,256,0,stream>>>(P, flag);
        p ^= 1;
    }

    // ---- head ----
    out_head<<<192,256,0,stream>>>(pout, dlinb, d_out, flag);
}

// Round 4
// 1694.257 us; speedup vs baseline: 1.0575x; 1.0575x over previous
//
#include <hip/hip_runtime.h>
#include <hip/hip_bf16.h>
#include <math.h>

#define BN_ 8192
#define TT 18
#define NBITS 6
#define HH 256
#define G3 768

typedef __hip_bfloat16 hbf16;
typedef __bf16 bf16x8 __attribute__((ext_vector_type(8)));
typedef float f32x4 __attribute__((ext_vector_type(4)));

// r15: fast transcendentals. __expf -> v_exp_f32; error ~1e-7 abs, below bf16 quantum.
// ftanh(+-inf) exact: e=inf -> 1, e=0 -> -1.
__device__ inline float sigm(float x){ return 1.0f/(1.0f + __expf(-x)); }
__device__ inline float ftanh(float x){ float e = __expf(2.0f*x); return 1.0f - 2.0f/(e + 1.0f); }
__device__ inline float ldx(const void* p, int i, int bf){
    if(bf){ unsigned short u = ((const unsigned short*)p)[i]; return __uint_as_float(((unsigned)u)<<16); }
    return ((const float*)p)[i];
}
__device__ inline __bf16 f2b(float f){ hbf16 h = __float2bfloat16(f); return *reinterpret_cast<__bf16*>(&h); }
__device__ inline float b2f(__bf16 b){ unsigned short u = *reinterpret_cast<unsigned short*>(&b); return __uint_as_float(((unsigned)u)<<16); }
__device__ inline unsigned pack2(float a, float b){
    hbf16 lo = __float2bfloat16(a), hi = __float2bfloat16(b);
    return (unsigned)*(unsigned short*)&lo | ((unsigned)*(unsigned short*)&hi << 16);
}

// global->LDS direct DMA, 16B per lane. LDS dest must be wave-uniform base (+lane*16 by HW).
__device__ __forceinline__ void gld_lds16(const void* g, void* l){
    __builtin_amdgcn_global_load_lds(
        (const __attribute__((address_space(1))) unsigned int*)g,
        (__attribute__((address_space(3))) unsigned int*)l, 16, 0, 0);
}

// -------- fills --------
__global__ __launch_bounds__(256) void fillz(float* __restrict__ p, int n){
    for(int i = blockIdx.x*256 + threadIdx.x; i < n; i += gridDim.x*256) p[i] = 0.0f;
}
__global__ __launch_bounds__(256) void fillb(__bf16* __restrict__ p, int n){
    for(int i = blockIdx.x*256 + threadIdx.x; i < n; i += gridDim.x*256) p[i] = f2b(0.0f);
}

// -------- dtype detect + normalized per-step weights --------
__global__ void prep_w(const void* wp, const void* wm, unsigned* flag,
                       float* wpn, float* wfn, float* wbn){
    if(threadIdx.x==0 && blockIdx.x==0){
        unsigned w0 = *(const unsigned*)wp;               // weight_power is all-ones
        int bf = ((w0 >> 16) == (w0 & 0xFFFFu)) ? 1 : 0;
        flag[0] = (unsigned)bf;
        float s=0; for(int t=0;t<TT;t++){ float v=ldx(wp,t,bf); s += v*v; }
        for(int t=0;t<TT;t++){ float v=ldx(wp,t,bf); wpn[t] = sqrtf(v*v*TT/s); }
        float sf=0, sb=0;
        for(int t=0;t<TT;t++){ float f=ldx(wm,2*t,bf), b=ldx(wm,2*t+1,bf); sf += f*f; sb += b*b; }
        for(int t=0;t<TT;t++){
            float f=ldx(wm,2*t,bf), b=ldx(wm,2*t+1,bf);
            wfn[t] = sqrtf(f*f*TT/sf);
            wbn[t] = sqrtf(b*b*TT/sb);
        }
    }
}

// -------- conversions: mode1 = weight row-perm -> bf16; mode0 = bias f32; mode2 = [B,T]->[T,B] f32 --------
struct CJ { const void* src; void* dst; int n; int K; int mode; };
struct CJs { CJ j[20]; };
__global__ __launch_bounds__(256) void conv_all(CJs J, const unsigned* __restrict__ flagp){
    const int bf = (int)*flagp;
    CJ c = J.j[blockIdx.y];
    for(int i = blockIdx.x*256 + threadIdx.x; i < c.n; i += gridDim.x*256){
        if(c.mode==1){
            int row = i / c.K, k = i - row*c.K;
            int g = row>>8, jj = row&255;
            int prow = ((jj>>4)*48) + g*16 + (jj&15);
            ((__bf16*)c.dst)[(size_t)prow*c.K + k] = f2b(ldx(c.src, i, bf));
        }else if(c.mode==2){
            int t = i >> 13, b = i & (BN_-1);
            ((float*)c.dst)[i] = ldx(c.src, b*TT + t, bf);
        }else{
            ((float*)c.dst)[i] = ldx(c.src, i, bf);
        }
    }
}

// -------- fused recurrent step: dual GEMM (gi, gh) + GRU cell + LDS-coalesced epilogue --------
// r12: global_load_lds staging (linear LDS dest + inverse-swizzled global src + swizzled read).
// r13: stats_emit folded into MODE0 prologue; head projection folded into MODE3.
// r14: BK=32 double-buffered prefetch (neutral - TLP already hid latency; kept for structure).
// r15: (1) fast transcendentals (precise expf/tanhf were ~100 VALU instr per (row,j) in the
//      epilogue = ~200us total); (2) MODE2/3 get __launch_bounds__(256,4): 1024-block g2
//      dispatches need 4 blocks/CU residency to avoid a ~33% staggered tail; MODE3 live set
//      (acc 64 + frags 28) fits the 128-VGPR budget.
// MODE 0: enc layer0 (gh GEMM; gi = rank-7 from bits/z) + prev-step BN stats -> h, yseq[t-1]
// MODE 1: enc layer1 (gi,gh GEMMs) -> h + rowdot atomics into xt
// MODE 2: dec layer0 (gh GEMM; gi = y*wih+bih)                 -> h + s1 slice
// MODE 3: dec layer1 (gi K=512, gh K=256)                      -> h + head partials
struct FQ {
    const __bf16* A1; const __bf16* W1; int K1;   // K1 doubles as stats_on for MODE0
    const __bf16* A2; const __bf16* W2; int K2;
    const float* bgi; const float* bgh;
    const __bf16* h; __bf16* hout;
    const void* bits; const void* wih0raw; const void* bih0raw;                    // mode0 (bits=dlinW in mode3)
    const void* linw; float* xt;       // mode1: enc_lin row-dot dest | mode0: linw=elinb, xt=xtR | mode3: xt=pout_part
    const float* y; const void* wihraw; const void* bihraw; __bf16* s1t;           // mode2 | mode0: y=n1p, wihraw=n2p, s1t=yseq dest
    float* racc; const float* wct;     // mode0: racc=xtZ, wct=&wpn[t-1] | mode3: wct=&w_merge[t]
};
struct FQ2 { FQ q[2]; };

template<int MODE>
__global__ __launch_bounds__(256, (MODE>=2) ? 4 : 3) void fused_step(FQ2 PP, const unsigned* __restrict__ flagp){
    const FQ P = PP.q[blockIdx.z];
    const int bf = (int)*flagp;
    __shared__ __align__(16) char smem[28672];   // 2 x (A 8192 + W 6144) double buffer
    __shared__ float zs[192];                   // mode0: z feedback per row (128) | mode3: W-head slice (192)
    __shared__ float sred[4], ssred[4];
    float*  T  = (float*)smem;                  // 128*33*4 = 16896 (reused after K-loop)
    const int tid = threadIdx.x;
    // XCD-aware swizzle: XCD = blockIdx.x -> contiguous m-band per XCD.
    const int mt = blockIdx.x*8 + (blockIdx.y>>3);
    const int jt = blockIdx.y & 7;
    const int m0 = mt*128;
    const int n0 = jt*96;
    const int lane = tid&63, wv = tid>>6;
    const int wvbase = tid & ~63;               // wv*64, wave-uniform
    const int wrow = wv>>1, wcol = wv&1;        // wave: 64 rows x 48 cols
    const int q = lane>>4, n15 = lane&15;

    // ---- pipelined K-loop geometry (compile-time) ----
    constexpr int S1  = (MODE==1) ? 8 : (MODE==3 ? 16 : 0);   // BK32 steps in phase0 (gi GEMM)
    constexpr int NST = S1 + 8;                               // + phase1 (gh GEMM, K=256)
    constexpr int KD1 = (MODE==3) ? 512 : 256;
    constexpr int KD2 = 256;
    const __bf16* pA1 = (S1>0) ? P.A1 + (size_t)m0*KD1 : (const __bf16*)nullptr;
    const __bf16* pW1 = (S1>0) ? P.W1 + (size_t)n0*KD1 : (const __bf16*)nullptr;
    const __bf16* pA2 = P.A2 + (size_t)m0*KD2;
    const __bf16* pW2 = P.W2 + (size_t)n0*KD2;
    const int r0 = tid>>2, sl0 = tid&3;              // chunk c = tid
    const int q0 = sl0 ^ ((r0>>1)&3);
    const int r1 = (256+tid)>>2, sl1 = tid&3;        // chunk c = 256+tid
    const int q1 = sl1 ^ ((r1>>1)&3);

    auto STG = [&](int s){
        const __bf16* A; const __bf16* W; int K; int k0;
        if(s < S1){ A = pA1; W = pW1; K = KD1; k0 = s*32; }
        else      { A = pA2; W = pW2; K = KD2; k0 = (s-S1)*32; }
        char* buf = smem + (s&1)*14336;
        // A-tile: 128x32 bf16 = 8192 B = 512 chunks (2/thread)
        gld_lds16(A + (size_t)r0*K + k0 + q0*8, buf + (size_t)wvbase*16);
        gld_lds16(A + (size_t)r1*K + k0 + q1*8, buf + (size_t)(256+wvbase)*16);
        // W-tile: 96x32 bf16 = 6144 B = 384 chunks (1.5/thread; waves 0,1 take the extra)
        gld_lds16(W + (size_t)r0*K + k0 + q0*8, buf + 8192 + (size_t)wvbase*16);
        if(tid < 128)
            gld_lds16(W + (size_t)r1*K + k0 + q1*8, buf + 8192 + (size_t)(256+wvbase)*16);
    };

    STG(0);   // prologue prefetch; drained by the next __syncthreads

    // ---- MODE0 prologue: redundant per-block BN stats of previous step (replaces stats_emit) ----
    if(MODE==0){
        if(P.K1){
            const float lbv = ldx(P.linw, 0, bf);
            const float wt  = P.wct[0];
            const float* __restrict__ xr = P.xt;
            float s=0.0f, ss=0.0f;
            const float4* x4 = (const float4*)xr;
            for(int i=tid;i<BN_/4;i+=256){
                float4 vv = x4[i];
                float a0=ftanh(vv.x+lbv), a1=ftanh(vv.y+lbv), a2=ftanh(vv.z+lbv), a3=ftanh(vv.w+lbv);
                s += a0+a1+a2+a3; ss += a0*a0+a1*a1+a2*a2+a3*a3;
            }
            #pragma unroll
            for(int o=32;o;o>>=1){ s += __shfl_xor(s,o); ss += __shfl_xor(ss,o); }
            if(lane==0){ sred[wv]=s; ssred[wv]=ss; }
            __syncthreads();
            float a = sred[0]+sred[1]+sred[2]+sred[3];
            float bq = ssred[0]+ssred[1]+ssred[2]+ssred[3];
            float mean = a/(float)BN_;
            float var = (bq - (float)BN_*mean*mean)/(float)(BN_-1);
            float rs = 1.0f/sqrtf(var);
            if(tid<128){
                int row = m0 + tid;
                float v = ftanh(xr[row]+lbv);
                float yv = (v-mean)*rs*wt + P.y[row];
                zs[tid] = yv + ((const float*)P.wihraw)[row];
                if(jt==0){ ((float*)P.s1t)[row] = yv; P.racc[row] = 0.0f; }
            }
        }else{
            if(tid<128) zs[tid] = 0.0f;
        }
        __syncthreads();
    }else{
        __syncthreads();
    }

    f32x4 accR[4], accZ[4], accN1[4], accN2[4];
    #pragma unroll
    for(int i=0;i<4;i++){ accR[i]=(f32x4){0,0,0,0}; accZ[i]=(f32x4){0,0,0,0};
                          accN1[i]=(f32x4){0,0,0,0}; accN2[i]=(f32x4){0,0,0,0}; }

    // ---- main pipelined loop: STAGE(s+1) || compute(s) ----
    #pragma unroll
    for(int s=0; s<NST; ++s){
        if(s+1 < NST) STG(s+1);
        const char* buf = smem + (s&1)*14336;
        const __bf16* Asb = (const __bf16*)buf;
        const __bf16* Wsb = (const __bf16*)(buf + 8192);
        bf16x8 af[4], bfr[3];
        #pragma unroll
        for(int i=0;i<4;i++){
            int R = wrow*64+i*16+n15;
            int col = q ^ ((R>>1)&3);
            af[i] = *(const bf16x8*)&Asb[R*32 + col*8];
        }
        #pragma unroll
        for(int g=0;g<3;g++){
            int RW = wcol*48+g*16+n15;
            int col = q ^ ((RW>>1)&3);
            bfr[g] = *(const bf16x8*)&Wsb[RW*32 + col*8];
        }
        #pragma unroll
        for(int i=0;i<4;i++){
            accR[i] = __builtin_amdgcn_mfma_f32_16x16x32_bf16(af[i], bfr[0], accR[i], 0,0,0);
            accZ[i] = __builtin_amdgcn_mfma_f32_16x16x32_bf16(af[i], bfr[1], accZ[i], 0,0,0);
            if(s < S1) accN1[i] = __builtin_amdgcn_mfma_f32_16x16x32_bf16(af[i], bfr[2], accN1[i], 0,0,0);
            else       accN2[i] = __builtin_amdgcn_mfma_f32_16x16x32_bf16(af[i], bfr[2], accN2[i], 0,0,0);
        }
        __syncthreads();
    }

    // ---- epilogue compute: lane owns hidden unit j for 16 rows; hn -> T (f32) ----
    const int jl = wcol*16 + n15;
    const int j  = jt*32 + jl;
    const float bghr = P.bgh[j], bghz = P.bgh[256+j], bghn = P.bgh[512+j];
    float bgir=0, bgiz=0, bgin=0;
    if(MODE==1 || MODE==3){ bgir = P.bgi[j]; bgiz = P.bgi[256+j]; bgin = P.bgi[512+j]; }
    float w0r[7], w0z[7], w0n[7];
    if(MODE==0){
        #pragma unroll
        for(int k=0;k<7;k++){
            w0r[k] = ldx(P.wih0raw, (j    )*7+k, bf);
            w0z[k] = ldx(P.wih0raw, (j+256)*7+k, bf);
            w0n[k] = ldx(P.wih0raw, (j+512)*7+k, bf);
        }
        bgir = ldx(P.bih0raw, j, bf); bgiz = ldx(P.bih0raw, j+256, bf); bgin = ldx(P.bih0raw, j+512, bf);
    }
    float wy_r=0, wy_z=0, wy_n=0;
    if(MODE==2){
        wy_r = ldx(P.wihraw, j, bf); wy_z = ldx(P.wihraw, j+256, bf); wy_n = ldx(P.wihraw, j+512, bf);
        bgir = ldx(P.bihraw, j, bf); bgiz = ldx(P.bihraw, j+256, bf); bgin = ldx(P.bihraw, j+512, bf);
    }
    const float linwj = (MODE==1) ? ldx(P.linw, j, bf) : 0.0f;

    #pragma unroll
    for(int i=0;i<4;i++){
        const int rbl = wrow*64 + i*16 + q*4;
        float vred[4];
        #pragma unroll
        for(int r=0;r<4;r++){
            const int row_l = rbl + r;
            const int row = m0 + row_l;
            float gir, giz, gin;
            if(MODE==1 || MODE==3){
                gir = bgir; giz = bgiz; gin = accN1[i][r] + bgin;
            }else if(MODE==0){
                gir = bgir; giz = bgiz; gin = bgin;
                #pragma unroll
                for(int k=0;k<NBITS;k++){
                    float bv = ldx(P.bits, row*NBITS+k, bf);
                    gir += bv*w0r[k]; giz += bv*w0z[k]; gin += bv*w0n[k];
                }
                float zb = zs[row_l];
                gir += zb*w0r[6]; giz += zb*w0z[6]; gin += zb*w0n[6];
            }else{ // MODE==2
                float yv = P.y[row];
                gir = yv*wy_r + bgir; giz = yv*wy_z + bgiz; gin = yv*wy_n + bgin;
            }
            float rr = sigm(gir + accR[i][r] + bghr);
            float zz = sigm(giz + accZ[i][r] + bghz);
            float nn = ftanh(gin + rr*(accN2[i][r] + bghn));
            float hold = b2f(P.h[(size_t)row*HH + j]);
            float hn = (1.0f - zz)*nn + zz*hold;
            T[row_l*33 + jl] = hn;
            if(MODE==1) vred[r] = hn*linwj;
        }
        if(MODE==1){
            #pragma unroll
            for(int r=0;r<4;r++){
                float v = vred[r];
                #pragma unroll
                for(int m=1;m<16;m<<=1) v += __shfl_xor(v, m);
                if(n15==0) atomicAdd(&P.xt[m0+rbl+r], v);
            }
        }
    }
    if(MODE==3 && tid<192){   // stage dlinW slice: k=tid>>5 (6 rows), 32 cols of this block
        int k = tid>>5, jj = tid&31;
        zs[tid] = ldx(P.bits, k*512 + (int)blockIdx.z*256 + jt*32 + jj, bf);
    }
    __syncthreads();

    // ---- coalesced write-out: 4 lanes per row x 8 j each ----
    const int rw2 = tid>>2, cw = tid&3;
    #pragma unroll
    for(int pass=0; pass<2; pass++){
        const int row_l = pass*64 + rw2;
        const int row = m0 + row_l;
        float v[8];
        #pragma unroll
        for(int u=0;u<8;u++) v[u] = T[row_l*33 + cw*8 + u];
        uint4 pkv = { pack2(v[0],v[1]), pack2(v[2],v[3]), pack2(v[4],v[5]), pack2(v[6],v[7]) };
        *(uint4*)&P.hout[(size_t)row*HH + jt*32 + cw*8] = pkv;
        if(MODE==2) *(uint4*)&P.s1t[(size_t)row*512 + jt*32 + cw*8] = pkv;
    }
    if(MODE==3){
        // head partial: pp[(row,k)] += wct * (T-row . W-slice). Private (jt,z) slice -> no atomics.
        float* pp = P.xt + (size_t)(jt + 8*(int)blockIdx.z)*(BN_*NBITS);
        const float wct3 = P.wct[0];
        #pragma unroll
        for(int u=0;u<3;u++){
            int idx = tid + 256*u;
            int row_l = idx/6, k = idx - row_l*6;
            float dot = 0.0f;
            #pragma unroll
            for(int jj=0;jj<32;jj++) dot += T[row_l*33+jj]*zs[k*32+jj];
            size_t gi = (size_t)(m0+row_l)*NBITS + k;
            pp[gi] += wct3*dot;
        }
    }
}

// -------- fused tanh + batch-norm stats (ddof=1) + y emit; only used for the final step t=17 --------
__global__ __launch_bounds__(1024) void stats_emit(float* __restrict__ xt, const void* __restrict__ lb,
        const float* __restrict__ wpn, int t, const float* __restrict__ n1t, const float* __restrict__ n2t,
        float* __restrict__ yseq, float* __restrict__ zf, const unsigned* __restrict__ flagp){
    const int bf = (int)*flagp;
    const float lbv = ldx(lb, 0, bf);
    int tid = threadIdx.x;
    float s=0.0f, ss=0.0f;
    for(int i=tid;i<BN_;i+=1024){ float v = ftanh(xt[i] + lbv); s += v; ss += v*v; }
    #pragma unroll
    for(int o=32;o;o>>=1){ s += __shfl_down(s,o); ss += __shfl_down(ss,o); }
    __shared__ float S[16], SS[16], stm[2];
    if((tid&63)==0){ S[tid>>6]=s; SS[tid>>6]=ss; }
    __syncthreads();
    if(tid==0){
        float a=0.0f, b=0.0f;
        for(int i=0;i<16;i++){ a+=S[i]; b+=SS[i]; }
        float mean = a/(float)BN_;
        float var = (b - (float)BN_*mean*mean)/(float)(BN_-1);
        stm[0]=mean; stm[1]=1.0f/sqrtf(var);
    }
    __syncthreads();
    const float mean=stm[0], rs=stm[1], wt=wpn[t];
    for(int i=tid;i<BN_;i+=1024){
        float v = ftanh(xt[i] + lbv);
        float y = (v-mean)*rs*wt + n1t[i];
        yseq[(size_t)t*BN_ + i] = y;
        zf[i] = y + n2t[i];
        xt[i] = 0.0f;
    }
}

// -------- head: sum 16 partial slices + bias + sigmoid --------
__global__ __launch_bounds__(256) void out_head(const float* __restrict__ pp, const void* __restrict__ bias,
        void* __restrict__ out, const unsigned* __restrict__ flagp){
    const int bf = (int)*flagp;
    int i = blockIdx.x*256 + threadIdx.x;
    if(i >= BN_*NBITS) return;
    float s = 0.0f;
    #pragma unroll
    for(int k=0;k<16;k++) s += pp[(size_t)k*(BN_*NBITS) + i];
    int kk = i - (i/6)*6;
    float v = sigm(s + ldx(bias, kk, bf));
    if(bf) ((hbf16*)out)[i] = __float2bfloat16(v);
    else   ((float*)out)[i] = v;
}

extern "C" void kernel_launch(void* const* d_in, const int* in_sizes, int n_in,
                              void* d_out, int out_size, void* d_ws, size_t ws_size,
                              hipStream_t stream)
{
    (void)in_sizes; (void)n_in; (void)out_size;
    const void* bits  = d_in[0];
    const void* n1    = d_in[1];
    const void* n2    = d_in[2];
    const void* eWih0 = d_in[3];
    const void* eWhh0 = d_in[4];
    const void* ebih0 = d_in[5];
    const void* ebhh0 = d_in[6];
    const void* eWih1 = d_in[7];
    const void* eWhh1 = d_in[8];
    const void* ebih1 = d_in[9];
    const void* ebhh1 = d_in[10];
    const void* elinW = d_in[11];
    const void* elinb = d_in[12];
    const void* wpow  = d_in[13];
    const void* dWih0f= d_in[14];
    const void* dWhh0f= d_in[15];
    const void* dbih0f= d_in[16];
    const void* dbhh0f= d_in[17];
    const void* dWih0b= d_in[18];
    const void* dWhh0b= d_in[19];
    const void* dbih0b= d_in[20];
    const void* dbhh0b= d_in[21];
    const void* dWih1f= d_in[22];
    const void* dWhh1f= d_in[23];
    const void* dbih1f= d_in[24];
    const void* dbhh1f= d_in[25];
    const void* dWih1b= d_in[26];
    const void* dWhh1b= d_in[27];
    const void* dbih1b= d_in[28];
    const void* dbhh1b= d_in[29];
    const void* dlinW = d_in[30];
    const void* dlinb = d_in[31];
    const void* wmrg  = d_in[32];

    float* base = (float*)d_ws;
    size_t off = 0;
    auto alloc  = [&](size_t n){ float* p = base + off; off += (n + 63) & ~(size_t)63; return p; };
    auto allocb = [&](size_t n){ __bf16* p = (__bf16*)(base + off); off += ((n/2) + 63) & ~(size_t)63; return p; };
    unsigned* flag = (unsigned*)alloc(64);
    float* wpn = alloc(TT); float* wfn = alloc(TT); float* wbn = alloc(TT);
    const int WK = HH*G3;   // 196608
    __bf16* WeHH0 = allocb(WK);  __bf16* WeIH1 = allocb(WK);  __bf16* WeHH1 = allocb(WK);
    __bf16* Wd0f  = allocb(WK);  __bf16* Wd0b  = allocb(WK);
    __bf16* Wd1fI = allocb(2*WK);__bf16* Wd1bI = allocb(2*WK);
    __bf16* Wd1fH = allocb(WK);  __bf16* Wd1bH = allocb(WK);
    float* BeHH0 = alloc(G3); float* BeIH1 = alloc(G3); float* BeHH1 = alloc(G3);
    float* Bd0f  = alloc(G3); float* Bd0b  = alloc(G3);
    float* Bd1fI = alloc(G3); float* Bd1bI = alloc(G3);
    float* Bd1fH = alloc(G3); float* Bd1bH = alloc(G3);
    const size_t NH = (size_t)BN_*HH;
    __bf16* X0 = allocb(NH);  __bf16* X1 = allocb(NH);
    __bf16* Y0 = allocb(NH);  __bf16* Y1 = allocb(NH);
    float* pout = alloc((size_t)16*BN_*NBITS);            // 16 head-partial slices
    float* xtA = alloc(BN_);
    float* xtB = alloc(BN_);
    float* zf  = alloc(BN_);
    float* yseq= alloc((size_t)TT*BN_);
    float* n1t = alloc((size_t)TT*BN_);
    float* n2t = alloc((size_t)TT*BN_);
    __bf16* s1 = allocb((size_t)TT*BN_*512);
    size_t need = off*sizeof(float);
    if(ws_size < need) return;

    // ---- prep ----
    prep_w<<<1,64,0,stream>>>(wpow, wmrg, flag, wpn, wfn, wbn);
    CJs J;
    const void* ws_src[20] = {eWhh0,eWih1,eWhh1,dWhh0f,dWhh0b,dWih1f,dWih1b,dWhh1f,dWhh1b,
                              ebhh0,ebih1,ebhh1,dbhh0f,dbhh0b,dbih1f,dbih1b,dbhh1f,dbhh1b, n1, n2};
    void* ws_dst[20] = {WeHH0,WeIH1,WeHH1,Wd0f,Wd0b,Wd1fI,Wd1bI,Wd1fH,Wd1bH,
                        BeHH0,BeIH1,BeHH1,Bd0f,Bd0b,Bd1fI,Bd1bI,Bd1fH,Bd1bH, n1t, n2t};
    int ws_n[20] = {WK,WK,WK,WK,WK,2*WK,2*WK,WK,WK, G3,G3,G3,G3,G3,G3,G3,G3,G3, TT*BN_, TT*BN_};
    int ws_K[20] = {256,256,256,256,256,512,512,256,256, 0,0,0,0,0,0,0,0,0, 0,0};
    int ws_m[20] = {1,1,1,1,1,1,1,1,1, 0,0,0,0,0,0,0,0,0, 2,2};
    for(int i=0;i<20;i++){ J.j[i] = {ws_src[i], ws_dst[i], ws_n[i], ws_K[i], ws_m[i]}; }
    conv_all<<<dim3(768,20),256,0,stream>>>(J, flag);
    fillb<<<1024,256,0,stream>>>(X0, (int)NH);
    fillb<<<1024,256,0,stream>>>(Y0, (int)NH);
    fillz<<<32,256,0,stream>>>(xtA, BN_);
    fillz<<<32,256,0,stream>>>(xtB, BN_);
    fillz<<<192,256,0,stream>>>(pout, 16*BN_*NBITS);

    dim3 g1(8, 64, 1), g2(8, 64, 2);
    __bf16* X[2] = {X0, X1};
    __bf16* Y[2] = {Y0, Y1};
    float* xts[2] = {xtA, xtB};

    // ---- encoder: 18 steps, 2 dispatches each (stats fused into next MODE0) ----
    int p = 0;
    for(int t=0;t<TT;t++){
        FQ2 P0{}; FQ2 P1{};
        FQ& a = P0.q[0];
        a.A2=X[p]; a.W2=WeHH0; a.K2=HH; a.bgh=BeHH0; a.h=X[p]; a.hout=X[1-p];
        a.bits=bits; a.wih0raw=eWih0; a.bih0raw=ebih0;
        a.K1 = (t>0) ? 1 : 0;
        if(t>0){
            a.xt   = xts[(t-1)&1];                       // stats source (prev MODE1 atomics)
            a.racc = xts[t&1];                           // zero target (consumed by prev MODE0)
            a.y    = n1t + (size_t)(t-1)*BN_;
            a.wihraw = (const void*)(n2t + (size_t)(t-1)*BN_);
            a.s1t  = (__bf16*)(yseq + (size_t)(t-1)*BN_);
            a.wct  = wpn + (t-1);
            a.linw = elinb;
        }
        fused_step<0><<<g1,256,0,stream>>>(P0, flag);
        FQ& b = P1.q[0];
        b.A1=X[1-p]; b.W1=WeIH1; b.K1=HH; b.A2=Y[p]; b.W2=WeHH1; b.K2=HH;
        b.bgi=BeIH1; b.bgh=BeHH1; b.h=Y[p]; b.hout=Y[1-p];
        b.linw=elinW; b.xt=xts[t&1];
        fused_step<1><<<g1,256,0,stream>>>(P1, flag);
        p ^= 1;
    }
    stats_emit<<<1,1024,0,stream>>>(xts[(TT-1)&1], elinb, wpn, TT-1,
                                    n1t+(size_t)(TT-1)*BN_, n2t+(size_t)(TT-1)*BN_, yseq, zf, flag);

    // ---- decoder layer0: fwd (X) + bwd (Y) in one z=2 dispatch per step ----
    fillb<<<1024,256,0,stream>>>(X0, (int)NH);
    fillb<<<1024,256,0,stream>>>(Y0, (int)NH);
    p = 0;
    for(int i=0;i<TT;i++){
        int tf = i, tb = TT-1-i;
        FQ2 P{};
        FQ& a = P.q[0];
        a.A2=X[p]; a.W2=Wd0f; a.K2=HH; a.bgh=Bd0f; a.h=X[p]; a.hout=X[1-p];
        a.y=yseq+(size_t)tf*BN_; a.wihraw=dWih0f; a.bihraw=dbih0f; a.s1t=s1+(size_t)tf*BN_*512;
        FQ& b = P.q[1];
        b.A2=Y[p]; b.W2=Wd0b; b.K2=HH; b.bgh=Bd0b; b.h=Y[p]; b.hout=Y[1-p];
        b.y=yseq+(size_t)tb*BN_; b.wihraw=dWih0b; b.bihraw=dbih0b; b.s1t=s1+(size_t)tb*BN_*512+256;
        fused_step<2><<<g2,256,0,stream>>>(P, flag);
        p ^= 1;
    }

    // ---- decoder layer1: fwd (X) + bwd (Y) in one z=2 dispatch per step, head partials fused ----
    fillb<<<1024,256,0,stream>>>(X0, (int)NH);
    fillb<<<1024,256,0,stream>>>(Y0, (int)NH);
    p = 0;
    for(int i=0;i<TT;i++){
        int tf = i, tb = TT-1-i;
        FQ2 P{};
        FQ& a = P.q[0];
        a.A1=s1+(size_t)tf*BN_*512; a.W1=Wd1fI; a.K1=512;
        a.A2=X[p]; a.W2=Wd1fH; a.K2=HH; a.bgi=Bd1fI; a.bgh=Bd1fH; a.h=X[p]; a.hout=X[1-p];
        a.bits=dlinW; a.xt=pout; a.wct=wfn+tf;
        FQ& b = P.q[1];
        b.A1=s1+(size_t)tb*BN_*512; b.W1=Wd1bI; b.K1=512;
        b.A2=Y[p]; b.W2=Wd1bH; b.K2=HH; b.bgi=Bd1bI; b.bgh=Bd1bH; b.h=Y[p]; b.hout=Y[1-p];
        b.bits=dlinW; b.xt=pout; b.wct=wbn+tb;
        fused_step<3><<<g2,256,0,stream>>>(P, flag);
        p ^= 1;
    }

    // ---- head ----
    out_head<<<192,256,0,stream>>>(pout, dlinb, d_out, flag);
}

// Round 5
// 1673.932 us; speedup vs baseline: 1.0703x; 1.0121x over previous
//
#include <hip/hip_runtime.h>
#include <hip/hip_bf16.h>
#include <math.h>

#define BN_ 8192
#define TT 18
#define NBITS 6
#define HH 256
#define G3 768

typedef __hip_bfloat16 hbf16;
typedef __bf16 bf16x8 __attribute__((ext_vector_type(8)));
typedef float f32x4 __attribute__((ext_vector_type(4)));

// r15: fast transcendentals. __expf -> v_exp_f32; error ~1e-7 abs, below bf16 quantum.
__device__ inline float sigm(float x){ return 1.0f/(1.0f + __expf(-x)); }
__device__ inline float ftanh(float x){ float e = __expf(2.0f*x); return 1.0f - 2.0f/(e + 1.0f); }
__device__ inline float ldx(const void* p, int i, int bf){
    if(bf){ unsigned short u = ((const unsigned short*)p)[i]; return __uint_as_float(((unsigned)u)<<16); }
    return ((const float*)p)[i];
}
__device__ inline __bf16 f2b(float f){ hbf16 h = __float2bfloat16(f); return *reinterpret_cast<__bf16*>(&h); }
__device__ inline float b2f(__bf16 b){ unsigned short u = *reinterpret_cast<unsigned short*>(&b); return __uint_as_float(((unsigned)u)<<16); }
__device__ inline unsigned pack2(float a, float b){
    hbf16 lo = __float2bfloat16(a), hi = __float2bfloat16(b);
    return (unsigned)*(unsigned short*)&lo | ((unsigned)*(unsigned short*)&hi << 16);
}

// global->LDS direct DMA, 16B per lane. LDS dest must be wave-uniform base (+lane*16 by HW).
__device__ __forceinline__ void gld_lds16(const void* g, void* l){
    __builtin_amdgcn_global_load_lds(
        (const __attribute__((address_space(1))) unsigned int*)g,
        (__attribute__((address_space(3))) unsigned int*)l, 16, 0, 0);
}

// -------- fills --------
__global__ __launch_bounds__(256) void fillz(float* __restrict__ p, int n){
    for(int i = blockIdx.x*256 + threadIdx.x; i < n; i += gridDim.x*256) p[i] = 0.0f;
}
__global__ __launch_bounds__(256) void fillb(__bf16* __restrict__ p, int n){
    for(int i = blockIdx.x*256 + threadIdx.x; i < n; i += gridDim.x*256) p[i] = f2b(0.0f);
}

// -------- dtype detect + normalized per-step weights --------
__global__ void prep_w(const void* wp, const void* wm, unsigned* flag,
                       float* wpn, float* wfn, float* wbn){
    if(threadIdx.x==0 && blockIdx.x==0){
        unsigned w0 = *(const unsigned*)wp;               // weight_power is all-ones
        int bf = ((w0 >> 16) == (w0 & 0xFFFFu)) ? 1 : 0;
        flag[0] = (unsigned)bf;
        float s=0; for(int t=0;t<TT;t++){ float v=ldx(wp,t,bf); s += v*v; }
        for(int t=0;t<TT;t++){ float v=ldx(wp,t,bf); wpn[t] = sqrtf(v*v*TT/s); }
        float sf=0, sb=0;
        for(int t=0;t<TT;t++){ float f=ldx(wm,2*t,bf), b=ldx(wm,2*t+1,bf); sf += f*f; sb += b*b; }
        for(int t=0;t<TT;t++){
            float f=ldx(wm,2*t,bf), b=ldx(wm,2*t+1,bf);
            wfn[t] = sqrtf(f*f*TT/sf);
            wbn[t] = sqrtf(b*b*TT/sb);
        }
    }
}

// -------- conversions: mode1 = weight row-perm -> bf16; mode0 = bias f32; mode2 = [B,T]->[T,B] f32 --------
struct CJ { const void* src; void* dst; int n; int K; int mode; };
struct CJs { CJ j[20]; };
__global__ __launch_bounds__(256) void conv_all(CJs J, const unsigned* __restrict__ flagp){
    const int bf = (int)*flagp;
    CJ c = J.j[blockIdx.y];
    for(int i = blockIdx.x*256 + threadIdx.x; i < c.n; i += gridDim.x*256){
        if(c.mode==1){
            int row = i / c.K, k = i - row*c.K;
            int g = row>>8, jj = row&255;
            int prow = ((jj>>4)*48) + g*16 + (jj&15);
            ((__bf16*)c.dst)[(size_t)prow*c.K + k] = f2b(ldx(c.src, i, bf));
        }else if(c.mode==2){
            int t = i >> 13, b = i & (BN_-1);
            ((float*)c.dst)[i] = ldx(c.src, b*TT + t, bf);
        }else{
            ((float*)c.dst)[i] = ldx(c.src, i, bf);
        }
    }
}

// -------- fused recurrent step: dual GEMM (gi, gh) + GRU cell + LDS-coalesced epilogue --------
// r12: global_load_lds staging (linear LDS dest + inverse-swizzled global src + swizzled read).
// r13: stats_emit folded into MODE0 prologue; head projection folded into MODE3.
// r14: BK=32 double-buffered prefetch.
// r15: fast transcendentals; decoder __launch_bounds__(256,4).
// r16: encoder tile BM 128->64 (templated). Encoder grids: 512 -> 1024 blocks = exactly
//      4 blocks/CU: waves/SIMD 2 -> 4 (was the minimum-TLP regime; every latency half-exposed).
//      Decoder keeps BM=128 (W-traffic doubles with smaller tiles; no TLP gain there).
// MODE 0 (BM=64):  enc layer0 (gh GEMM; gi = rank-7 from bits/z) + prev-step BN stats
// MODE 1 (BM=64):  enc layer1 (gi,gh GEMMs) -> h + rowdot atomics into xt
// MODE 2 (BM=128): dec layer0 (gh GEMM; gi = y*wih+bih)  -> h + s1 slice
// MODE 3 (BM=128): dec layer1 (gi K=512, gh K=256)       -> h + head partials
struct FQ {
    const __bf16* A1; const __bf16* W1; int K1;   // K1 doubles as stats_on for MODE0
    const __bf16* A2; const __bf16* W2; int K2;
    const float* bgi; const float* bgh;
    const __bf16* h; __bf16* hout;
    const void* bits; const void* wih0raw; const void* bih0raw;                    // mode0 (bits=dlinW in mode3)
    const void* linw; float* xt;       // mode1: enc_lin row-dot dest | mode0: linw=elinb, xt=xtR | mode3: xt=pout_part
    const float* y; const void* wihraw; const void* bihraw; __bf16* s1t;           // mode2 | mode0: y=n1p, wihraw=n2p, s1t=yseq dest
    float* racc; const float* wct;     // mode0: racc=xtZ, wct=&wpn[t-1] | mode3: wct=&w_merge[t]
};
struct FQ2 { FQ q[2]; };

template<int MODE>
__global__ __launch_bounds__(256,4) void fused_step(FQ2 PP, const unsigned* __restrict__ flagp){
    const FQ P = PP.q[blockIdx.z];
    const int bf = (int)*flagp;
    constexpr int BM   = (MODE<=1) ? 64 : 128;   // tile rows
    constexpr int NF   = BM/32;                  // A row-frags per wave
    constexpr int ABYT = BM*64;                  // A tile bytes (BM x 32 bf16)
    constexpr int BUFB = ABYT + 6144;            // + W tile (96 x 32 bf16)
    __shared__ __align__(16) char smem[28672];   // 2 x BUFB (max 28672 at BM=128)
    __shared__ float zs[192];                   // mode0: z feedback per row | mode3: W-head slice
    __shared__ float sred[4], ssred[4];
    float*  T  = (float*)smem;                  // BM*33*4 (reused after K-loop)
    const int tid = threadIdx.x;
    // XCD-aware swizzle: XCD = blockIdx.x -> contiguous m-band per XCD.
    constexpr int MTS = (8192/BM)/8;
    const int mt = blockIdx.x*MTS + (blockIdx.y>>3);
    const int jt = blockIdx.y & 7;
    const int m0 = mt*BM;
    const int n0 = jt*96;
    const int lane = tid&63, wv = tid>>6;
    const int wvbase = tid & ~63;               // wv*64, wave-uniform
    const int wrow = wv>>1, wcol = wv&1;        // wave: BM/2 rows x 48 W-rows
    const int q = lane>>4, n15 = lane&15;

    // ---- pipelined K-loop geometry (compile-time) ----
    constexpr int S1  = (MODE==1) ? 8 : (MODE==3 ? 16 : 0);   // BK32 steps in phase0 (gi GEMM)
    constexpr int NST = S1 + 8;                               // + phase1 (gh GEMM, K=256)
    constexpr int KD1 = (MODE==3) ? 512 : 256;
    constexpr int KD2 = 256;
    const __bf16* pA1 = (S1>0) ? P.A1 + (size_t)m0*KD1 : (const __bf16*)nullptr;
    const __bf16* pW1 = (S1>0) ? P.W1 + (size_t)n0*KD1 : (const __bf16*)nullptr;
    const __bf16* pA2 = P.A2 + (size_t)m0*KD2;
    const __bf16* pW2 = P.W2 + (size_t)n0*KD2;
    const int r0 = tid>>2, sl0 = tid&3;              // chunk c = tid
    const int q0 = sl0 ^ ((r0>>1)&3);
    const int r1 = 64 + r0;                          // chunk c = 256+tid
    const int q1 = sl0 ^ ((r1>>1)&3);

    auto STG = [&](int s){
        const __bf16* A; const __bf16* W; int K; int k0;
        if(s < S1){ A = pA1; W = pW1; K = KD1; k0 = s*32; }
        else      { A = pA2; W = pW2; K = KD2; k0 = (s-S1)*32; }
        char* buf = smem + (s&1)*BUFB;
        // A-tile: BM x 32 bf16 = BM*4 chunks
        gld_lds16(A + (size_t)r0*K + k0 + q0*8, buf + (size_t)wvbase*16);
        if constexpr(BM==128)
            gld_lds16(A + (size_t)r1*K + k0 + q1*8, buf + (size_t)(256+wvbase)*16);
        // W-tile: 96 x 32 bf16 = 384 chunks (1.5/thread; waves 0,1 take the extra)
        gld_lds16(W + (size_t)r0*K + k0 + q0*8, buf + ABYT + (size_t)wvbase*16);
        if(tid < 128)
            gld_lds16(W + (size_t)r1*K + k0 + q1*8, buf + ABYT + (size_t)(256+wvbase)*16);
    };

    STG(0);   // prologue prefetch; drained by the next __syncthreads

    // ---- MODE0 prologue: redundant per-block BN stats of previous step (replaces stats_emit) ----
    if(MODE==0){
        if(P.K1){
            const float lbv = ldx(P.linw, 0, bf);
            const float wt  = P.wct[0];
            const float* __restrict__ xr = P.xt;
            float s=0.0f, ss=0.0f;
            const float4* x4 = (const float4*)xr;
            for(int i=tid;i<BN_/4;i+=256){
                float4 vv = x4[i];
                float a0=ftanh(vv.x+lbv), a1=ftanh(vv.y+lbv), a2=ftanh(vv.z+lbv), a3=ftanh(vv.w+lbv);
                s += a0+a1+a2+a3; ss += a0*a0+a1*a1+a2*a2+a3*a3;
            }
            #pragma unroll
            for(int o=32;o;o>>=1){ s += __shfl_xor(s,o); ss += __shfl_xor(ss,o); }
            if(lane==0){ sred[wv]=s; ssred[wv]=ss; }
            __syncthreads();
            float a = sred[0]+sred[1]+sred[2]+sred[3];
            float bq = ssred[0]+ssred[1]+ssred[2]+ssred[3];
            float mean = a/(float)BN_;
            float var = (bq - (float)BN_*mean*mean)/(float)(BN_-1);
            float rs = 1.0f/sqrtf(var);
            if(tid<BM){
                int row = m0 + tid;
                float v = ftanh(xr[row]+lbv);
                float yv = (v-mean)*rs*wt + P.y[row];
                zs[tid] = yv + ((const float*)P.wihraw)[row];
                if(jt==0){ ((float*)P.s1t)[row] = yv; P.racc[row] = 0.0f; }
            }
        }else{
            if(tid<BM) zs[tid] = 0.0f;
        }
        __syncthreads();
    }else{
        __syncthreads();
    }

    f32x4 accR[NF], accZ[NF], accN1[NF], accN2[NF];
    #pragma unroll
    for(int i=0;i<NF;i++){ accR[i]=(f32x4){0,0,0,0}; accZ[i]=(f32x4){0,0,0,0};
                           accN1[i]=(f32x4){0,0,0,0}; accN2[i]=(f32x4){0,0,0,0}; }

    // ---- main pipelined loop: STAGE(s+1) || compute(s) ----
    #pragma unroll
    for(int s=0; s<NST; ++s){
        if(s+1 < NST) STG(s+1);
        const char* buf = smem + (s&1)*BUFB;
        const __bf16* Asb = (const __bf16*)buf;
        const __bf16* Wsb = (const __bf16*)(buf + ABYT);
        bf16x8 af[NF], bfr[3];
        #pragma unroll
        for(int i=0;i<NF;i++){
            int R = wrow*(BM/2)+i*16+n15;
            int col = q ^ ((R>>1)&3);
            af[i] = *(const bf16x8*)&Asb[R*32 + col*8];
        }
        #pragma unroll
        for(int g=0;g<3;g++){
            int RW = wcol*48+g*16+n15;
            int col = q ^ ((RW>>1)&3);
            bfr[g] = *(const bf16x8*)&Wsb[RW*32 + col*8];
        }
        #pragma unroll
        for(int i=0;i<NF;i++){
            accR[i] = __builtin_amdgcn_mfma_f32_16x16x32_bf16(af[i], bfr[0], accR[i], 0,0,0);
            accZ[i] = __builtin_amdgcn_mfma_f32_16x16x32_bf16(af[i], bfr[1], accZ[i], 0,0,0);
            if(s < S1) accN1[i] = __builtin_amdgcn_mfma_f32_16x16x32_bf16(af[i], bfr[2], accN1[i], 0,0,0);
            else       accN2[i] = __builtin_amdgcn_mfma_f32_16x16x32_bf16(af[i], bfr[2], accN2[i], 0,0,0);
        }
        __syncthreads();
    }

    // ---- epilogue compute: lane owns hidden unit j for NF*4 rows; hn -> T (f32) ----
    const int jl = wcol*16 + n15;
    const int j  = jt*32 + jl;
    const float bghr = P.bgh[j], bghz = P.bgh[256+j], bghn = P.bgh[512+j];
    float bgir=0, bgiz=0, bgin=0;
    if(MODE==1 || MODE==3){ bgir = P.bgi[j]; bgiz = P.bgi[256+j]; bgin = P.bgi[512+j]; }
    float w0r[7], w0z[7], w0n[7];
    if(MODE==0){
        #pragma unroll
        for(int k=0;k<7;k++){
            w0r[k] = ldx(P.wih0raw, (j    )*7+k, bf);
            w0z[k] = ldx(P.wih0raw, (j+256)*7+k, bf);
            w0n[k] = ldx(P.wih0raw, (j+512)*7+k, bf);
        }
        bgir = ldx(P.bih0raw, j, bf); bgiz = ldx(P.bih0raw, j+256, bf); bgin = ldx(P.bih0raw, j+512, bf);
    }
    float wy_r=0, wy_z=0, wy_n=0;
    if(MODE==2){
        wy_r = ldx(P.wihraw, j, bf); wy_z = ldx(P.wihraw, j+256, bf); wy_n = ldx(P.wihraw, j+512, bf);
        bgir = ldx(P.bihraw, j, bf); bgiz = ldx(P.bihraw, j+256, bf); bgin = ldx(P.bihraw, j+512, bf);
    }
    const float linwj = (MODE==1) ? ldx(P.linw, j, bf) : 0.0f;

    #pragma unroll
    for(int i=0;i<NF;i++){
        const int rbl = wrow*(BM/2) + i*16 + q*4;
        float vred[4];
        #pragma unroll
        for(int r=0;r<4;r++){
            const int row_l = rbl + r;
            const int row = m0 + row_l;
            float gir, giz, gin;
            if(MODE==1 || MODE==3){
                gir = bgir; giz = bgiz; gin = accN1[i][r] + bgin;
            }else if(MODE==0){
                gir = bgir; giz = bgiz; gin = bgin;
                #pragma unroll
                for(int k=0;k<NBITS;k++){
                    float bv = ldx(P.bits, row*NBITS+k, bf);
                    gir += bv*w0r[k]; giz += bv*w0z[k]; gin += bv*w0n[k];
                }
                float zb = zs[row_l];
                gir += zb*w0r[6]; giz += zb*w0z[6]; gin += zb*w0n[6];
            }else{ // MODE==2
                float yv = P.y[row];
                gir = yv*wy_r + bgir; giz = yv*wy_z + bgiz; gin = yv*wy_n + bgin;
            }
            float rr = sigm(gir + accR[i][r] + bghr);
            float zz = sigm(giz + accZ[i][r] + bghz);
            float nn = ftanh(gin + rr*(accN2[i][r] + bghn));
            float hold = b2f(P.h[(size_t)row*HH + j]);
            float hn = (1.0f - zz)*nn + zz*hold;
            T[row_l*33 + jl] = hn;
            if(MODE==1) vred[r] = hn*linwj;
        }
        if(MODE==1){
            #pragma unroll
            for(int r=0;r<4;r++){
                float v = vred[r];
                #pragma unroll
                for(int m=1;m<16;m<<=1) v += __shfl_xor(v, m);
                if(n15==0) atomicAdd(&P.xt[m0+rbl+r], v);
            }
        }
    }
    if(MODE==3 && tid<192){   // stage dlinW slice: k=tid>>5 (6 rows), 32 cols of this block
        int k = tid>>5, jj = tid&31;
        zs[tid] = ldx(P.bits, k*512 + (int)blockIdx.z*256 + jt*32 + jj, bf);
    }
    __syncthreads();

    // ---- coalesced write-out: 4 lanes per row x 8 j each ----
    const int rw2 = tid>>2, cw = tid&3;
    #pragma unroll
    for(int pass=0; pass<BM/64; pass++){
        const int row_l = pass*64 + rw2;
        const int row = m0 + row_l;
        float v[8];
        #pragma unroll
        for(int u=0;u<8;u++) v[u] = T[row_l*33 + cw*8 + u];
        uint4 pkv = { pack2(v[0],v[1]), pack2(v[2],v[3]), pack2(v[4],v[5]), pack2(v[6],v[7]) };
        *(uint4*)&P.hout[(size_t)row*HH + jt*32 + cw*8] = pkv;
        if(MODE==2) *(uint4*)&P.s1t[(size_t)row*512 + jt*32 + cw*8] = pkv;
    }
    if(MODE==3){
        // head partial: pp[(row,k)] += wct * (T-row . W-slice). Private (jt,z) slice -> no atomics.
        float* pp = P.xt + (size_t)(jt + 8*(int)blockIdx.z)*(BN_*NBITS);
        const float wct3 = P.wct[0];
        #pragma unroll
        for(int u=0;u<3;u++){
            int idx = tid + 256*u;
            int row_l = idx/6, k = idx - row_l*6;
            float dot = 0.0f;
            #pragma unroll
            for(int jj=0;jj<32;jj++) dot += T[row_l*33+jj]*zs[k*32+jj];
            size_t gi = (size_t)(m0+row_l)*NBITS + k;
            pp[gi] += wct3*dot;
        }
    }
}

// -------- fused tanh + batch-norm stats (ddof=1) + y emit; only used for the final step t=17 --------
__global__ __launch_bounds__(1024) void stats_emit(float* __restrict__ xt, const void* __restrict__ lb,
        const float* __restrict__ wpn, int t, const float* __restrict__ n1t, const float* __restrict__ n2t,
        float* __restrict__ yseq, float* __restrict__ zf, const unsigned* __restrict__ flagp){
    const int bf = (int)*flagp;
    const float lbv = ldx(lb, 0, bf);
    int tid = threadIdx.x;
    float s=0.0f, ss=0.0f;
    for(int i=tid;i<BN_;i+=1024){ float v = ftanh(xt[i] + lbv); s += v; ss += v*v; }
    #pragma unroll
    for(int o=32;o;o>>=1){ s += __shfl_down(s,o); ss += __shfl_down(ss,o); }
    __shared__ float S[16], SS[16], stm[2];
    if((tid&63)==0){ S[tid>>6]=s; SS[tid>>6]=ss; }
    __syncthreads();
    if(tid==0){
        float a=0.0f, b=0.0f;
        for(int i=0;i<16;i++){ a+=S[i]; b+=SS[i]; }
        float mean = a/(float)BN_;
        float var = (b - (float)BN_*mean*mean)/(float)(BN_-1);
        stm[0]=mean; stm[1]=1.0f/sqrtf(var);
    }
    __syncthreads();
    const float mean=stm[0], rs=stm[1], wt=wpn[t];
    for(int i=tid;i<BN_;i+=1024){
        float v = ftanh(xt[i] + lbv);
        float y = (v-mean)*rs*wt + n1t[i];
        yseq[(size_t)t*BN_ + i] = y;
        zf[i] = y + n2t[i];
        xt[i] = 0.0f;
    }
}

// -------- head: sum 16 partial slices + bias + sigmoid --------
__global__ __launch_bounds__(256) void out_head(const float* __restrict__ pp, const void* __restrict__ bias,
        void* __restrict__ out, const unsigned* __restrict__ flagp){
    const int bf = (int)*flagp;
    int i = blockIdx.x*256 + threadIdx.x;
    if(i >= BN_*NBITS) return;
    float s = 0.0f;
    #pragma unroll
    for(int k=0;k<16;k++) s += pp[(size_t)k*(BN_*NBITS) + i];
    int kk = i - (i/6)*6;
    float v = sigm(s + ldx(bias, kk, bf));
    if(bf) ((hbf16*)out)[i] = __float2bfloat16(v);
    else   ((float*)out)[i] = v;
}

extern "C" void kernel_launch(void* const* d_in, const int* in_sizes, int n_in,
                              void* d_out, int out_size, void* d_ws, size_t ws_size,
                              hipStream_t stream)
{
    (void)in_sizes; (void)n_in; (void)out_size;
    const void* bits  = d_in[0];
    const void* n1    = d_in[1];
    const void* n2    = d_in[2];
    const void* eWih0 = d_in[3];
    const void* eWhh0 = d_in[4];
    const void* ebih0 = d_in[5];
    const void* ebhh0 = d_in[6];
    const void* eWih1 = d_in[7];
    const void* eWhh1 = d_in[8];
    const void* ebih1 = d_in[9];
    const void* ebhh1 = d_in[10];
    const void* elinW = d_in[11];
    const void* elinb = d_in[12];
    const void* wpow  = d_in[13];
    const void* dWih0f= d_in[14];
    const void* dWhh0f= d_in[15];
    const void* dbih0f= d_in[16];
    const void* dbhh0f= d_in[17];
    const void* dWih0b= d_in[18];
    const void* dWhh0b= d_in[19];
    const void* dbih0b= d_in[20];
    const void* dbhh0b= d_in[21];
    const void* dWih1f= d_in[22];
    const void* dWhh1f= d_in[23];
    const void* dbih1f= d_in[24];
    const void* dbhh1f= d_in[25];
    const void* dWih1b= d_in[26];
    const void* dWhh1b= d_in[27];
    const void* dbih1b= d_in[28];
    const void* dbhh1b= d_in[29];
    const void* dlinW = d_in[30];
    const void* dlinb = d_in[31];
    const void* wmrg  = d_in[32];

    float* base = (float*)d_ws;
    size_t off = 0;
    auto alloc  = [&](size_t n){ float* p = base + off; off += (n + 63) & ~(size_t)63; return p; };
    auto allocb = [&](size_t n){ __bf16* p = (__bf16*)(base + off); off += ((n/2) + 63) & ~(size_t)63; return p; };
    unsigned* flag = (unsigned*)alloc(64);
    float* wpn = alloc(TT); float* wfn = alloc(TT); float* wbn = alloc(TT);
    const int WK = HH*G3;   // 196608
    __bf16* WeHH0 = allocb(WK);  __bf16* WeIH1 = allocb(WK);  __bf16* WeHH1 = allocb(WK);
    __bf16* Wd0f  = allocb(WK);  __bf16* Wd0b  = allocb(WK);
    __bf16* Wd1fI = allocb(2*WK);__bf16* Wd1bI = allocb(2*WK);
    __bf16* Wd1fH = allocb(WK);  __bf16* Wd1bH = allocb(WK);
    float* BeHH0 = alloc(G3); float* BeIH1 = alloc(G3); float* BeHH1 = alloc(G3);
    float* Bd0f  = alloc(G3); float* Bd0b  = alloc(G3);
    float* Bd1fI = alloc(G3); float* Bd1bI = alloc(G3);
    float* Bd1fH = alloc(G3); float* Bd1bH = alloc(G3);
    const size_t NH = (size_t)BN_*HH;
    __bf16* X0 = allocb(NH);  __bf16* X1 = allocb(NH);
    __bf16* Y0 = allocb(NH);  __bf16* Y1 = allocb(NH);
    float* pout = alloc((size_t)16*BN_*NBITS);            // 16 head-partial slices
    float* xtA = alloc(BN_);
    float* xtB = alloc(BN_);
    float* zf  = alloc(BN_);
    float* yseq= alloc((size_t)TT*BN_);
    float* n1t = alloc((size_t)TT*BN_);
    float* n2t = alloc((size_t)TT*BN_);
    __bf16* s1 = allocb((size_t)TT*BN_*512);
    size_t need = off*sizeof(float);
    if(ws_size < need) return;

    // ---- prep ----
    prep_w<<<1,64,0,stream>>>(wpow, wmrg, flag, wpn, wfn, wbn);
    CJs J;
    const void* ws_src[20] = {eWhh0,eWih1,eWhh1,dWhh0f,dWhh0b,dWih1f,dWih1b,dWhh1f,dWhh1b,
                              ebhh0,ebih1,ebhh1,dbhh0f,dbhh0b,dbih1f,dbih1b,dbhh1f,dbhh1b, n1, n2};
    void* ws_dst[20] = {WeHH0,WeIH1,WeHH1,Wd0f,Wd0b,Wd1fI,Wd1bI,Wd1fH,Wd1bH,
                        BeHH0,BeIH1,BeHH1,Bd0f,Bd0b,Bd1fI,Bd1bI,Bd1fH,Bd1bH, n1t, n2t};
    int ws_n[20] = {WK,WK,WK,WK,WK,2*WK,2*WK,WK,WK, G3,G3,G3,G3,G3,G3,G3,G3,G3, TT*BN_, TT*BN_};
    int ws_K[20] = {256,256,256,256,256,512,512,256,256, 0,0,0,0,0,0,0,0,0, 0,0};
    int ws_m[20] = {1,1,1,1,1,1,1,1,1, 0,0,0,0,0,0,0,0,0, 2,2};
    for(int i=0;i<20;i++){ J.j[i] = {ws_src[i], ws_dst[i], ws_n[i], ws_K[i], ws_m[i]}; }
    conv_all<<<dim3(768,20),256,0,stream>>>(J, flag);
    fillb<<<1024,256,0,stream>>>(X0, (int)NH);
    fillb<<<1024,256,0,stream>>>(Y0, (int)NH);
    fillz<<<32,256,0,stream>>>(xtA, BN_);
    fillz<<<32,256,0,stream>>>(xtB, BN_);
    fillz<<<192,256,0,stream>>>(pout, 16*BN_*NBITS);

    dim3 g1(8, 128, 1), g2(8, 64, 2);    // BM=64 encoder, BM=128 decoder
    __bf16* X[2] = {X0, X1};
    __bf16* Y[2] = {Y0, Y1};
    float* xts[2] = {xtA, xtB};

    // ---- encoder: 18 steps, 2 dispatches each (stats fused into next MODE0) ----
    int p = 0;
    for(int t=0;t<TT;t++){
        FQ2 P0{}; FQ2 P1{};
        FQ& a = P0.q[0];
        a.A2=X[p]; a.W2=WeHH0; a.K2=HH; a.bgh=BeHH0; a.h=X[p]; a.hout=X[1-p];
        a.bits=bits; a.wih0raw=eWih0; a.bih0raw=ebih0;
        a.K1 = (t>0) ? 1 : 0;
        if(t>0){
            a.xt   = xts[(t-1)&1];                       // stats source (prev MODE1 atomics)
            a.racc = xts[t&1];                           // zero target (consumed by prev MODE0)
            a.y    = n1t + (size_t)(t-1)*BN_;
            a.wihraw = (const void*)(n2t + (size_t)(t-1)*BN_);
            a.s1t  = (__bf16*)(yseq + (size_t)(t-1)*BN_);
            a.wct  = wpn + (t-1);
            a.linw = elinb;
        }
        fused_step<0><<<g1,256,0,stream>>>(P0, flag);
        FQ& b = P1.q[0];
        b.A1=X[1-p]; b.W1=WeIH1; b.K1=HH; b.A2=Y[p]; b.W2=WeHH1; b.K2=HH;
        b.bgi=BeIH1; b.bgh=BeHH1; b.h=Y[p]; b.hout=Y[1-p];
        b.linw=elinW; b.xt=xts[t&1];
        fused_step<1><<<g1,256,0,stream>>>(P1, flag);
        p ^= 1;
    }
    stats_emit<<<1,1024,0,stream>>>(xts[(TT-1)&1], elinb, wpn, TT-1,
                                    n1t+(size_t)(TT-1)*BN_, n2t+(size_t)(TT-1)*BN_, yseq, zf, flag);

    // ---- decoder layer0: fwd (X) + bwd (Y) in one z=2 dispatch per step ----
    fillb<<<1024,256,0,stream>>>(X0, (int)NH);
    fillb<<<1024,256,0,stream>>>(Y0, (int)NH);
    p = 0;
    for(int i=0;i<TT;i++){
        int tf = i, tb = TT-1-i;
        FQ2 P{};
        FQ& a = P.q[0];
        a.A2=X[p]; a.W2=Wd0f; a.K2=HH; a.bgh=Bd0f; a.h=X[p]; a.hout=X[1-p];
        a.y=yseq+(size_t)tf*BN_; a.wihraw=dWih0f; a.bihraw=dbih0f; a.s1t=s1+(size_t)tf*BN_*512;
        FQ& b = P.q[1];
        b.A2=Y[p]; b.W2=Wd0b; b.K2=HH; b.bgh=Bd0b; b.h=Y[p]; b.hout=Y[1-p];
        b.y=yseq+(size_t)tb*BN_; b.wihraw=dWih0b; b.bihraw=dbih0b; b.s1t=s1+(size_t)tb*BN_*512+256;
        fused_step<2><<<g2,256,0,stream>>>(P, flag);
        p ^= 1;
    }

    // ---- decoder layer1: fwd (X) + bwd (Y) in one z=2 dispatch per step, head partials fused ----
    fillb<<<1024,256,0,stream>>>(X0, (int)NH);
    fillb<<<1024,256,0,stream>>>(Y0, (int)NH);
    p = 0;
    for(int i=0;i<TT;i++){
        int tf = i, tb = TT-1-i;
        FQ2 P{};
        FQ& a = P.q[0];
        a.A1=s1+(size_t)tf*BN_*512; a.W1=Wd1fI; a.K1=512;
        a.A2=X[p]; a.W2=Wd1fH; a.K2=HH; a.bgi=Bd1fI; a.bgh=Bd1fH; a.h=X[p]; a.hout=X[1-p];
        a.bits=dlinW; a.xt=pout; a.wct=wfn+tf;
        FQ& b = P.q[1];
        b.A1=s1+(size_t)tb*BN_*512; b.W1=Wd1bI; b.K1=512;
        b.A2=Y[p]; b.W2=Wd1bH; b.K2=HH; b.bgi=Bd1bI; b.bgh=Bd1bH; b.h=Y[p]; b.hout=Y[1-p];
        b.bits=dlinW; b.xt=pout; b.wct=wbn+tb;
        fused_step<3><<<g2,256,0,stream>>>(P, flag);
        p ^= 1;
    }

    // ---- head ----
    out_head<<<192,256,0,stream>>>(pout, dlinb, d_out, flag);
}